// Round 5
// baseline (726.594 us; speedup 1.0000x reference)
//
#include <hip/hip_runtime.h>
#include <cstddef>

namespace {
constexpr int kNH  = 4;
constexpr int kKD  = 16;
constexpr int kHD  = 64;
constexpr int kD   = 64;
constexpr int kRES = 40;
constexpr int kN   = 1600;   // 40*40
constexpr int kB   = 16;
constexpr int kDIM = 256;
constexpr int kQT  = kN / 32;        // 50 query tiles
constexpr int kNC  = 5;              // key chunks (split-K)
constexpr int kTPC = kQT / kNC;      // 10 key tiles per chunk
constexpr float kEPS   = 1e-5f;
constexpr float kSCALE = 0.25f;          // KD^-0.5
constexpr float kLOG2E = 1.4426950408889634f;
constexpr float kC1    = kSCALE * kLOG2E;
}  // namespace

typedef __attribute__((ext_vector_type(8)))  short short8;
typedef __attribute__((ext_vector_type(4)))  float f32x4;
typedef __attribute__((ext_vector_type(16))) float f32x16;

// f32 -> bf16 bits, round-nearest-even (values here are finite).
static __device__ __forceinline__ unsigned short f2bf(float x) {
  unsigned u = __builtin_bit_cast(unsigned, x);
  u = (u + 0x7fffu + ((u >> 16) & 1u)) >> 16;
  return (unsigned short)u;
}

// ---------------------------------------------------------------------------
// Kernel 0: prep — bias2 = attn_bias*log2e; proj_w -> bf16; BN fold psc/psh.
// ---------------------------------------------------------------------------
__global__ __launch_bounds__(256) void prep_kernel(
    const float* __restrict__ attn_bias, const float* __restrict__ proj_w,
    const float* __restrict__ pg, const float* __restrict__ pb,
    const float* __restrict__ pm, const float* __restrict__ pv,
    float* __restrict__ bias2, unsigned short* __restrict__ w_bf,
    float* __restrict__ psc, float* __restrict__ psh) {
  const int i = blockIdx.x * 256 + threadIdx.x;
  if (i < kNH * kN) bias2[i] = attn_bias[i] * kLOG2E;
  if (i < kDIM * kDIM) w_bf[i] = f2bf(proj_w[i]);
  if (i < kDIM) {
    const float sc = pg[i] * rsqrtf(pv[i] + kEPS);
    psc[i] = sc;
    psh[i] = pb[i] - pm[i] * sc;
  }
}

// ---------------------------------------------------------------------------
// Kernel 1: depthwise 5x5 conv (SAME) + BN + cascade add (prev head output).
// ---------------------------------------------------------------------------
__global__ __launch_bounds__(256) void dwconv_bn_kernel(
    const float* __restrict__ x,
    const float* __restrict__ dw_w, const float* __restrict__ dw_g,
    const float* __restrict__ dw_b, const float* __restrict__ dw_m,
    const float* __restrict__ dw_v,
    const float* __restrict__ ohead,   // (B,256,N) f32 (cascade source)
    float* __restrict__ xi,            // (B,64,N) f32
    int head, int has_prev) {
  const int bc = blockIdx.x;           // b*64 + c
  const int b = bc >> 6;
  const int c = bc & 63;
  const int gc = head * kHD + c;

  const float* xin = x + ((size_t)b * kDIM + gc) * kN;
  const float* wc = dw_w + (size_t)gc * 25;
  float wreg[25];
#pragma unroll
  for (int t = 0; t < 25; ++t) wreg[t] = wc[t];

  const float sc = dw_g[gc] * rsqrtf(dw_v[gc] + kEPS);
  const float sh = dw_b[gc] - dw_m[gc] * sc;

  const float* prev = ohead + ((size_t)b * kDIM + (head - 1) * kD + c) * kN;
  float* xo = xi + ((size_t)b * kHD + c) * kN;

  for (int p = threadIdx.x; p < kN; p += blockDim.x) {
    const int h = p / kRES;
    const int w = p - h * kRES;
    float acc = 0.f;
#pragma unroll
    for (int dh = 0; dh < 5; ++dh) {
      const int hh = h + dh - 2;
      if (hh < 0 || hh >= kRES) continue;
#pragma unroll
      for (int dwi = 0; dwi < 5; ++dwi) {
        const int ww = w + dwi - 2;
        if (ww < 0 || ww >= kRES) continue;
        acc += xin[hh * kRES + ww] * wreg[dh * 5 + dwi];
      }
    }
    float val = acc * sc + sh;
    if (has_prev) val += prev[p];
    xo[p] = val;
  }
}

// ---------------------------------------------------------------------------
// Kernel 2a: Q,K 1x1 conv + BN -> bf16, transposed layout (b, n, 16).
// ---------------------------------------------------------------------------
__global__ __launch_bounds__(256) void qk_t_kernel(
    const float* __restrict__ xi,
    const float* __restrict__ q_w, const float* __restrict__ q_g,
    const float* __restrict__ q_b, const float* __restrict__ q_m,
    const float* __restrict__ q_v,
    const float* __restrict__ k_w, const float* __restrict__ k_g,
    const float* __restrict__ k_b, const float* __restrict__ k_m,
    const float* __restrict__ k_v,
    unsigned short* __restrict__ q_t, unsigned short* __restrict__ k_t,
    int head) {
  __shared__ float sw[2048];  // [0,1024) q weights, [1024,2048) k weights
  for (int i = threadIdx.x; i < 2048; i += 256)
    sw[i] = (i < 1024) ? q_w[(size_t)head * 1024 + i]
                       : k_w[(size_t)head * 1024 + (i - 1024)];
  __syncthreads();

  const int idx = blockIdx.x * 256 + threadIdx.x;  // b*1600 + n
  const int b = idx / kN;
  const float* xin = xi + (size_t)b * kHD * kN + (idx - b * kN);

  float qa[16] = {}, ka[16] = {};
  for (int c = 0; c < kHD; ++c) {
    const float xv = xin[(size_t)c * kN];
#pragma unroll
    for (int ch = 0; ch < 16; ++ch) {
      qa[ch] = fmaf(sw[ch * 64 + c], xv, qa[ch]);
      ka[ch] = fmaf(sw[1024 + ch * 64 + c], xv, ka[ch]);
    }
  }

  short8 qo0, qo1, ko0, ko1;
#pragma unroll
  for (int ch = 0; ch < 16; ++ch) {
    const int r = head * kKD + ch;
    const float qsc = q_g[r] * rsqrtf(q_v[r] + kEPS);
    const float qsh = q_b[r] - q_m[r] * qsc;
    const float ksc = k_g[r] * rsqrtf(k_v[r] + kEPS);
    const float ksh = k_b[r] - k_m[r] * ksc;
    const short qv2 = (short)f2bf(qa[ch] * qsc + qsh);
    const short kv2 = (short)f2bf(ka[ch] * ksc + ksh);
    if (ch < 8) { qo0[ch] = qv2; ko0[ch] = kv2; }
    else        { qo1[ch - 8] = qv2; ko1[ch - 8] = kv2; }
  }
  *(short8*)(q_t + (size_t)idx * 16)     = qo0;
  *(short8*)(q_t + (size_t)idx * 16 + 8) = qo1;
  *(short8*)(k_t + (size_t)idx * 16)     = ko0;
  *(short8*)(k_t + (size_t)idx * 16 + 8) = ko1;
}

// ---------------------------------------------------------------------------
// Kernel 2b: V 1x1 conv + BN -> bf16 (b, d, n), keys sigma-permuted within
// each 16-block (swap bits 2<->3 of n&15; involution).
// ---------------------------------------------------------------------------
__global__ __launch_bounds__(256) void v_perm_kernel(
    const float* __restrict__ xi,
    const float* __restrict__ v_w, const float* __restrict__ v_g,
    const float* __restrict__ v_b, const float* __restrict__ v_m,
    const float* __restrict__ v_v,
    unsigned short* __restrict__ v_p, int head) {
  const int idx = blockIdx.x * 256 + threadIdx.x;  // (b*64+d)*1600 + m
  const int m = idx % kN;
  const int t = idx / kN;    // b*64 + d
  const int d = t & 63;
  const int b = t >> 6;

  const int r = head * kD + d;
  const float* wrow = v_w + (size_t)r * kHD;
  const float* xin = xi + (size_t)b * kHD * kN + m;
  float acc = 0.f;
#pragma unroll 8
  for (int c = 0; c < kHD; ++c) acc = fmaf(wrow[c], xin[(size_t)c * kN], acc);
  const float sc = v_g[r] * rsqrtf(v_v[r] + kEPS);
  const float sh = v_b[r] - v_m[r] * sc;

  const int ml = m & 15;
  const int pos = (m & ~15) | (ml & 3) | ((ml & 4) << 1) | ((ml & 8) >> 1);
  v_p[(size_t)t * kN + pos] = f2bf(acc * sc + sh);
}

// ---------------------------------------------------------------------------
// Kernel 3a: split-K MFMA flash attention. One wave = 32 queries x 320 keys
// (10 tiles). Emits per-chunk partial (m, l, o[32]) — all lane-local.
// Wave id w -> b = w/250, qt = (w%250)/5, chunk = w%5.
// ---------------------------------------------------------------------------
__global__ __launch_bounds__(256) void attn_split_kernel(
    const unsigned short* __restrict__ q_t,
    const unsigned short* __restrict__ k_t,
    const unsigned short* __restrict__ v_p,
    const float* __restrict__ bias2,
    float* __restrict__ o_part,    // [B*QT*NC][64 lanes][32] f32
    float* __restrict__ ml_part,   // [B*QT*NC][64 lanes][2] f32
    int head) {
  const int lane = threadIdx.x & 63;
  const int wid = threadIdx.x >> 6;
  const int w = blockIdx.x * 4 + wid;
  if (w >= kB * kQT * kNC) return;
  const int b = w / (kQT * kNC);
  const int rem = w - b * (kQT * kNC);
  const int qt = rem / kNC;
  const int chunk = rem - qt * kNC;
  const int col = lane & 31;
  const int h = lane >> 5;
  const int nq = qt * 32 + col;

  const short8 qf =
      *(const short8*)(q_t + ((size_t)b * kN + nq) * 16 + h * 8);
  const float* bs = bias2 + (size_t)head * kN;
  const unsigned short* vb0 = v_p + ((size_t)(b * kD) + col) * kN;
  const unsigned short* vb1 = v_p + ((size_t)(b * kD) + 32 + col) * kN;

  f32x16 o0 = {}, o1 = {};
  float m = -3.0e38f, l = 0.f;

  for (int kt = chunk * kTPC; kt < (chunk + 1) * kTPC; ++kt) {
    const int kb = kt * 32;
    const short8 kf =
        *(const short8*)(k_t + ((size_t)b * kN + kb + col) * 16 + h * 8);
    f32x16 c = {};
    c = __builtin_amdgcn_mfma_f32_32x32x16_bf16(kf, qf, c, 0, 0, 0);

    const f32x4 bv0 = *(const f32x4*)(bs + kb + 4 * h);
    const f32x4 bv1 = *(const f32x4*)(bs + kb + 8 + 4 * h);
    const f32x4 bv2 = *(const f32x4*)(bs + kb + 16 + 4 * h);
    const f32x4 bv3 = *(const f32x4*)(bs + kb + 24 + 4 * h);

    float s[16];
#pragma unroll
    for (int r = 0; r < 4; ++r)  s[r]      = fmaf(c[r],      kC1, bv0[r]);
#pragma unroll
    for (int r = 0; r < 4; ++r)  s[4 + r]  = fmaf(c[4 + r],  kC1, bv1[r]);
#pragma unroll
    for (int r = 0; r < 4; ++r)  s[8 + r]  = fmaf(c[8 + r],  kC1, bv2[r]);
#pragma unroll
    for (int r = 0; r < 4; ++r)  s[12 + r] = fmaf(c[12 + r], kC1, bv3[r]);

    float tmax = s[0];
#pragma unroll
    for (int r = 1; r < 16; ++r) tmax = fmaxf(tmax, s[r]);
    tmax = fmaxf(tmax, __shfl_xor(tmax, 32));

    const bool upd = tmax > m + 8.0f;   // defer-max (log2 domain)
    if (__any(upd)) {
      const float alpha = upd ? exp2f(m - tmax) : 1.0f;
      m = upd ? tmax : m;
      l *= alpha;
#pragma unroll
      for (int r = 0; r < 16; ++r) { o0[r] *= alpha; o1[r] *= alpha; }
    }

    short8 p0, p1;
    float lsum = 0.f;
#pragma unroll
    for (int e = 0; e < 8; ++e) {
      const float pe = exp2f(s[e] - m);
      lsum += pe;
      p0[e] = (short)f2bf(pe);
    }
#pragma unroll
    for (int e = 0; e < 8; ++e) {
      const float pe = exp2f(s[8 + e] - m);
      lsum += pe;
      p1[e] = (short)f2bf(pe);
    }
    l += lsum;

    const short8 vf00 = *(const short8*)(vb0 + kb + h * 8);
    const short8 vf01 = *(const short8*)(vb0 + kb + 16 + h * 8);
    const short8 vf10 = *(const short8*)(vb1 + kb + h * 8);
    const short8 vf11 = *(const short8*)(vb1 + kb + 16 + h * 8);
    o0 = __builtin_amdgcn_mfma_f32_32x32x16_bf16(vf00, p0, o0, 0, 0, 0);
    o0 = __builtin_amdgcn_mfma_f32_32x32x16_bf16(vf01, p1, o0, 0, 0, 0);
    o1 = __builtin_amdgcn_mfma_f32_32x32x16_bf16(vf10, p0, o1, 0, 0, 0);
    o1 = __builtin_amdgcn_mfma_f32_32x32x16_bf16(vf11, p1, o1, 0, 0, 0);
  }

  l += __shfl_xor(l, 32);  // both halves now hold the query's full l

  float* op = o_part + (size_t)w * 2048 + lane * 32;
#pragma unroll
  for (int r = 0; r < 16; ++r) {
    op[r] = o0[r];
    op[16 + r] = o1[r];
  }
  ml_part[(size_t)w * 128 + lane * 2]     = m;
  ml_part[(size_t)w * 128 + lane * 2 + 1] = l;
}

// ---------------------------------------------------------------------------
// Kernel 3b: combine split-K partials + epilogue. One wave per (b, qt).
// Fully lane-local: each lane owns (col, h) and its 32 o-values.
// ---------------------------------------------------------------------------
__global__ __launch_bounds__(256) void attn_combine_kernel(
    const float* __restrict__ o_part, const float* __restrict__ ml_part,
    float* __restrict__ ohead, unsigned short* __restrict__ o_bf,
    int head, int wr_f32) {
  const int lane = threadIdx.x & 63;
  const int wid = threadIdx.x >> 6;
  const int w = blockIdx.x * 4 + wid;   // b*50 + qt
  if (w >= kB * kQT) return;
  const int b = w / kQT;
  const int qt = w - b * kQT;
  const int col = lane & 31;
  const int h = lane >> 5;
  const int nq = qt * 32 + col;

  const size_t base = (size_t)w * kNC;
  float mc[kNC], lc[kNC];
  float M = -3.0e38f;
#pragma unroll
  for (int c = 0; c < kNC; ++c) {
    mc[c] = ml_part[(base + c) * 128 + lane * 2];
    lc[c] = ml_part[(base + c) * 128 + lane * 2 + 1];
    M = fmaxf(M, mc[c]);
  }
  float o[32] = {};
  float l_tot = 0.f;
#pragma unroll
  for (int c = 0; c < kNC; ++c) {
    const float sc = exp2f(mc[c] - M);
    l_tot = fmaf(lc[c], sc, l_tot);
    const float* op = o_part + (base + c) * 2048 + lane * 32;
#pragma unroll
    for (int r = 0; r < 32; ++r) o[r] = fmaf(op[r], sc, o[r]);
  }
  const float inv = 1.0f / l_tot;

  float* ob = ohead + ((size_t)b * kDIM + head * kD) * kN + nq;
  unsigned short* obf = o_bf + ((size_t)b * kN + nq) * kDIM + head * kD;
#pragma unroll
  for (int r = 0; r < 16; ++r) {
    const int dim = (r & 3) + 8 * (r >> 2) + 4 * h;
    const float v0 = o[r] * inv;
    const float v1 = o[16 + r] * inv;
    if (wr_f32) {
      ob[(size_t)dim * kN] = v0;
      ob[(size_t)(32 + dim) * kN] = v1;
    }
    obf[dim] = f2bf(v0);
    obf[dim + 32] = f2bf(v1);
  }
}

// ---------------------------------------------------------------------------
// Kernel 4: projection GEMM via MFMA. C[o, (b,n)] = W[o,c] * o_bf[(b,n), c].
// ---------------------------------------------------------------------------
__global__ __launch_bounds__(256) void proj_mfma_kernel(
    const unsigned short* __restrict__ o_bf,   // (B, N, 256) bf16
    const unsigned short* __restrict__ w_bf,   // (256, 256) bf16
    const float* __restrict__ psc, const float* __restrict__ psh,
    float* __restrict__ out) {
  const int lane = threadIdx.x & 63;
  const int wid = threadIdx.x >> 6;
  const int t = blockIdx.x * 4 + wid;          // [0, 6400)
  const int b = t / 400;
  const int rem = t - b * 400;
  const int ot = rem / 50;
  const int nt = rem - ot * 50;
  const int col = lane & 31;
  const int h = lane >> 5;

  const unsigned short* arow = w_bf + ((size_t)(ot * 32 + col)) * kDIM + h * 8;
  const unsigned short* brow =
      o_bf + ((size_t)(b * kN + nt * 32 + col)) * kDIM + h * 8;

  f32x16 acc = {};
#pragma unroll
  for (int k = 0; k < 16; ++k) {
    const short8 af = *(const short8*)(arow + k * 16);
    const short8 bfr = *(const short8*)(brow + k * 16);
    acc = __builtin_amdgcn_mfma_f32_32x32x16_bf16(af, bfr, acc, 0, 0, 0);
  }

  float* ob = out + (size_t)b * kDIM * kN + nt * 32 + col;
#pragma unroll
  for (int r = 0; r < 16; ++r) {
    const int o = ot * 32 + (r & 3) + 8 * (r >> 2) + 4 * h;
    const float v = acc[r] * psc[o] + psh[o];
    ob[(size_t)o * kN] = fmaxf(v, 0.f);
  }
}

// ---------------------------------------------------------------------------
extern "C" void kernel_launch(void* const* d_in, const int* in_sizes, int n_in,
                              void* d_out, int out_size, void* d_ws,
                              size_t ws_size, hipStream_t stream) {
  const float* x      = (const float*)d_in[0];
  const float* dw_w   = (const float*)d_in[1];
  const float* dw_g   = (const float*)d_in[2];
  const float* dw_b   = (const float*)d_in[3];
  const float* dw_m   = (const float*)d_in[4];
  const float* dw_v   = (const float*)d_in[5];
  const float* q_w    = (const float*)d_in[6];
  const float* q_g    = (const float*)d_in[7];
  const float* q_b    = (const float*)d_in[8];
  const float* q_m    = (const float*)d_in[9];
  const float* q_v    = (const float*)d_in[10];
  const float* k_w    = (const float*)d_in[11];
  const float* k_g    = (const float*)d_in[12];
  const float* k_b    = (const float*)d_in[13];
  const float* k_m    = (const float*)d_in[14];
  const float* k_v    = (const float*)d_in[15];
  const float* v_w    = (const float*)d_in[16];
  const float* v_g    = (const float*)d_in[17];
  const float* v_b    = (const float*)d_in[18];
  const float* v_m    = (const float*)d_in[19];
  const float* v_v    = (const float*)d_in[20];
  const float* proj_w = (const float*)d_in[21];
  const float* proj_g = (const float*)d_in[22];
  const float* proj_b = (const float*)d_in[23];
  const float* proj_m = (const float*)d_in[24];
  const float* proj_v = (const float*)d_in[25];
  const float* attn_bias = (const float*)d_in[26];

  // Workspace layout (f32 region, then bf16 region, then split-K partials):
  float* ws = (float*)d_ws;
  float* xi_buf = ws;                                    // B*64*N f32
  float* ohead  = xi_buf + (size_t)kB * kHD * kN;        // B*256*N f32
  float* bias2  = ohead + (size_t)kB * kDIM * kN;        // 4*N f32
  float* psc    = bias2 + kNH * kN;                      // 256 f32
  float* psh    = psc + kDIM;                            // 256 f32
  unsigned short* q_t = (unsigned short*)(psh + kDIM);   // B*N*16 bf16
  unsigned short* k_t = q_t + (size_t)kB * kN * kKD;     // B*N*16 bf16
  unsigned short* v_p = k_t + (size_t)kB * kN * kKD;     // B*64*N bf16
  unsigned short* o_bf = v_p + (size_t)kB * kD * kN;     // B*N*256 bf16
  unsigned short* w_bf = o_bf + (size_t)kB * kN * kDIM;  // 256*256 bf16
  float* o_part = (float*)(w_bf + (size_t)kDIM * kDIM);  // B*50*5*2048 f32
  float* ml_part = o_part + (size_t)kB * kQT * kNC * 2048;  // B*50*5*128 f32

  prep_kernel<<<(kDIM * kDIM + 255) / 256, 256, 0, stream>>>(
      attn_bias, proj_w, proj_g, proj_b, proj_m, proj_v, bias2, w_bf, psc,
      psh);

  const int split_waves = kB * kQT * kNC;      // 4000
  const int comb_waves = kB * kQT;             // 800

  for (int head = 0; head < kNH; ++head) {
    dwconv_bn_kernel<<<kB * kHD, 256, 0, stream>>>(
        x, dw_w, dw_g, dw_b, dw_m, dw_v, ohead, xi_buf, head,
        head > 0 ? 1 : 0);

    qk_t_kernel<<<(kB * kN) / 256, 256, 0, stream>>>(
        xi_buf, q_w, q_g, q_b, q_m, q_v, k_w, k_g, k_b, k_m, k_v, q_t, k_t,
        head);

    v_perm_kernel<<<(kB * kD * kN) / 256, 256, 0, stream>>>(
        xi_buf, v_w, v_g, v_b, v_m, v_v, v_p, head);

    attn_split_kernel<<<split_waves / 4, 256, 0, stream>>>(
        q_t, k_t, v_p, bias2, o_part, ml_part, head);

    attn_combine_kernel<<<comb_waves / 4, 256, 0, stream>>>(
        o_part, ml_part, ohead, o_bf, head, head < 3 ? 1 : 0);
  }

  proj_mfma_kernel<<<1600, 256, 0, stream>>>(o_bf, w_bf, psc, psh,
                                             (float*)d_out);
}

// Round 6
// 591.863 us; speedup vs baseline: 1.2276x; 1.2276x over previous
//
#include <hip/hip_runtime.h>
#include <cstddef>

namespace {
constexpr int kNH  = 4;
constexpr int kKD  = 16;
constexpr int kHD  = 64;
constexpr int kD   = 64;
constexpr int kRES = 40;
constexpr int kN   = 1600;   // 40*40
constexpr int kB   = 16;
constexpr int kDIM = 256;
constexpr int kQT  = kN / 32;        // 50 query tiles
constexpr int kNC  = 5;              // key chunks (split-K)
constexpr int kTPC = kQT / kNC;      // 10 key tiles per chunk
constexpr float kEPS   = 1e-5f;
constexpr float kSCALE = 0.25f;          // KD^-0.5
constexpr float kLOG2E = 1.4426950408889634f;
constexpr float kC1    = kSCALE * kLOG2E;
}  // namespace

typedef __attribute__((ext_vector_type(8)))  short short8;
typedef __attribute__((ext_vector_type(4)))  float f32x4;
typedef __attribute__((ext_vector_type(16))) float f32x16;

// f32 -> bf16 bits, round-nearest-even (values here are finite).
static __device__ __forceinline__ unsigned short f2bf(float x) {
  unsigned u = __builtin_bit_cast(unsigned, x);
  u = (u + 0x7fffu + ((u >> 16) & 1u)) >> 16;
  return (unsigned short)u;
}

// ---------------------------------------------------------------------------
// Kernel 0: prep — bias2 = attn_bias*log2e; proj_w -> bf16; BN fold psc/psh.
// ---------------------------------------------------------------------------
__global__ __launch_bounds__(256) void prep_kernel(
    const float* __restrict__ attn_bias, const float* __restrict__ proj_w,
    const float* __restrict__ pg, const float* __restrict__ pb,
    const float* __restrict__ pm, const float* __restrict__ pv,
    float* __restrict__ bias2, unsigned short* __restrict__ w_bf,
    float* __restrict__ psc, float* __restrict__ psh) {
  const int i = blockIdx.x * 256 + threadIdx.x;
  if (i < kNH * kN) bias2[i] = attn_bias[i] * kLOG2E;
  if (i < kDIM * kDIM) w_bf[i] = f2bf(proj_w[i]);
  if (i < kDIM) {
    const float sc = pg[i] * rsqrtf(pv[i] + kEPS);
    psc[i] = sc;
    psh[i] = pb[i] - pm[i] * sc;
  }
}

// ---------------------------------------------------------------------------
// Kernel 1: depthwise 5x5 conv (SAME) + BN for ALL 4 heads at once.
// One block per (b, gc) with gc in [0,256). Image staged zero-padded
// (44x44) in LDS; 200 threads each compute one 8-pixel row segment
// (tap-reuse: 12 LDS reads per row of 5 taps x 8 pixels).
// Output cbn layout: (head, B, 64, N) — head slice contiguous.
// ---------------------------------------------------------------------------
__global__ __launch_bounds__(256) void conv_all_kernel(
    const float* __restrict__ x,
    const float* __restrict__ dw_w, const float* __restrict__ dw_g,
    const float* __restrict__ dw_b, const float* __restrict__ dw_m,
    const float* __restrict__ dw_v,
    float* __restrict__ cbn) {
  __shared__ float P[44 * 44];
  const int blk = blockIdx.x;          // b*256 + gc
  const int b = blk >> 8;
  const int gc = blk & 255;
  const int head = gc >> 6;
  const int c = gc & 63;
  const int tid = threadIdx.x;

  // zero-fill padded image
  for (int i = tid; i < 44 * 44; i += 256) P[i] = 0.f;
  __syncthreads();

  const float* xin = x + ((size_t)b * kDIM + gc) * kN;
  for (int i = tid; i < kN; i += 256) {
    const int r = i / kRES;
    const int col = i - r * kRES;
    P[(r + 2) * 44 + col + 2] = xin[i];
  }

  float wreg[25];
  const float* wc = dw_w + (size_t)gc * 25;
#pragma unroll
  for (int t = 0; t < 25; ++t) wreg[t] = wc[t];
  const float sc = dw_g[gc] * rsqrtf(dw_v[gc] + kEPS);
  const float sh = dw_b[gc] - dw_m[gc] * sc;

  __syncthreads();

  if (tid < 200) {
    const int h = tid / 5;             // row
    const int w0 = (tid - h * 5) * 8;  // segment start col
    float acc[8] = {};
#pragma unroll
    for (int dh = 0; dh < 5; ++dh) {
      float t[12];
      const float* row = P + (h + dh) * 44 + w0;
#pragma unroll
      for (int i = 0; i < 12; ++i) t[i] = row[i];
#pragma unroll
      for (int j = 0; j < 8; ++j)
#pragma unroll
        for (int i = 0; i < 5; ++i)
          acc[j] = fmaf(t[j + i], wreg[dh * 5 + i], acc[j]);
    }
    float* xo = cbn + ((size_t)head * kB * kHD + (size_t)b * kHD + c) * kN +
                h * kRES + w0;
    f32x4 o0, o1;
#pragma unroll
    for (int j = 0; j < 4; ++j) {
      o0[j] = acc[j] * sc + sh;
      o1[j] = acc[4 + j] * sc + sh;
    }
    *(f32x4*)xo = o0;
    *(f32x4*)(xo + 4) = o1;
  }
}

// ---------------------------------------------------------------------------
// Kernel 2a: Q,K 1x1 conv + BN -> bf16, transposed layout (b, n, 16).
// xi = cbn head slice (B, 64, N), possibly cascade-updated in place.
// ---------------------------------------------------------------------------
__global__ __launch_bounds__(256) void qk_t_kernel(
    const float* __restrict__ xi,
    const float* __restrict__ q_w, const float* __restrict__ q_g,
    const float* __restrict__ q_b, const float* __restrict__ q_m,
    const float* __restrict__ q_v,
    const float* __restrict__ k_w, const float* __restrict__ k_g,
    const float* __restrict__ k_b, const float* __restrict__ k_m,
    const float* __restrict__ k_v,
    unsigned short* __restrict__ q_t, unsigned short* __restrict__ k_t,
    int head) {
  __shared__ float sw[2048];  // [0,1024) q weights, [1024,2048) k weights
  for (int i = threadIdx.x; i < 2048; i += 256)
    sw[i] = (i < 1024) ? q_w[(size_t)head * 1024 + i]
                       : k_w[(size_t)head * 1024 + (i - 1024)];
  __syncthreads();

  const int idx = blockIdx.x * 256 + threadIdx.x;  // b*1600 + n
  const int b = idx / kN;
  const float* xin = xi + (size_t)b * kHD * kN + (idx - b * kN);

  float qa[16] = {}, ka[16] = {};
  for (int c = 0; c < kHD; ++c) {
    const float xv = xin[(size_t)c * kN];
#pragma unroll
    for (int ch = 0; ch < 16; ++ch) {
      qa[ch] = fmaf(sw[ch * 64 + c], xv, qa[ch]);
      ka[ch] = fmaf(sw[1024 + ch * 64 + c], xv, ka[ch]);
    }
  }

  short8 qo0, qo1, ko0, ko1;
#pragma unroll
  for (int ch = 0; ch < 16; ++ch) {
    const int r = head * kKD + ch;
    const float qsc = q_g[r] * rsqrtf(q_v[r] + kEPS);
    const float qsh = q_b[r] - q_m[r] * qsc;
    const float ksc = k_g[r] * rsqrtf(k_v[r] + kEPS);
    const float ksh = k_b[r] - k_m[r] * ksc;
    const short qv2 = (short)f2bf(qa[ch] * qsc + qsh);
    const short kv2 = (short)f2bf(ka[ch] * ksc + ksh);
    if (ch < 8) { qo0[ch] = qv2; ko0[ch] = kv2; }
    else        { qo1[ch - 8] = qv2; ko1[ch - 8] = kv2; }
  }
  *(short8*)(q_t + (size_t)idx * 16)     = qo0;
  *(short8*)(q_t + (size_t)idx * 16 + 8) = qo1;
  *(short8*)(k_t + (size_t)idx * 16)     = ko0;
  *(short8*)(k_t + (size_t)idx * 16 + 8) = ko1;
}

// ---------------------------------------------------------------------------
// Kernel 2b: V 1x1 conv + BN -> bf16 (b, d, n), keys sigma-permuted within
// each 16-block (swap bits 2<->3 of n&15; involution).
// ---------------------------------------------------------------------------
__global__ __launch_bounds__(256) void v_perm_kernel(
    const float* __restrict__ xi,
    const float* __restrict__ v_w, const float* __restrict__ v_g,
    const float* __restrict__ v_b, const float* __restrict__ v_m,
    const float* __restrict__ v_v,
    unsigned short* __restrict__ v_p, int head) {
  const int idx = blockIdx.x * 256 + threadIdx.x;  // (b*64+d)*1600 + m
  const int m = idx % kN;
  const int t = idx / kN;    // b*64 + d
  const int d = t & 63;
  const int b = t >> 6;

  const int r = head * kD + d;
  const float* wrow = v_w + (size_t)r * kHD;
  const float* xin = xi + (size_t)b * kHD * kN + m;
  float acc = 0.f;
#pragma unroll 8
  for (int c = 0; c < kHD; ++c) acc = fmaf(wrow[c], xin[(size_t)c * kN], acc);
  const float sc = v_g[r] * rsqrtf(v_v[r] + kEPS);
  const float sh = v_b[r] - v_m[r] * sc;

  const int ml = m & 15;
  const int pos = (m & ~15) | (ml & 3) | ((ml & 4) << 1) | ((ml & 8) >> 1);
  v_p[(size_t)t * kN + pos] = f2bf(acc * sc + sh);
}

// ---------------------------------------------------------------------------
// Kernel 3a: split-K MFMA flash attention. One wave = 32 queries x 320 keys
// (10 tiles). Emits per-chunk partial (m, l, o[32]) — all lane-local.
// ---------------------------------------------------------------------------
__global__ __launch_bounds__(256) void attn_split_kernel(
    const unsigned short* __restrict__ q_t,
    const unsigned short* __restrict__ k_t,
    const unsigned short* __restrict__ v_p,
    const float* __restrict__ bias2,
    float* __restrict__ o_part,    // [B*QT*NC][64 lanes][32] f32
    float* __restrict__ ml_part,   // [B*QT*NC][64 lanes][2] f32
    int head) {
  const int lane = threadIdx.x & 63;
  const int wid = threadIdx.x >> 6;
  const int w = blockIdx.x * 4 + wid;
  if (w >= kB * kQT * kNC) return;
  const int b = w / (kQT * kNC);
  const int rem = w - b * (kQT * kNC);
  const int qt = rem / kNC;
  const int chunk = rem - qt * kNC;
  const int col = lane & 31;
  const int h = lane >> 5;
  const int nq = qt * 32 + col;

  const short8 qf =
      *(const short8*)(q_t + ((size_t)b * kN + nq) * 16 + h * 8);
  const float* bs = bias2 + (size_t)head * kN;
  const unsigned short* vb0 = v_p + ((size_t)(b * kD) + col) * kN;
  const unsigned short* vb1 = v_p + ((size_t)(b * kD) + 32 + col) * kN;

  f32x16 o0 = {}, o1 = {};
  float m = -3.0e38f, l = 0.f;

  for (int kt = chunk * kTPC; kt < (chunk + 1) * kTPC; ++kt) {
    const int kb = kt * 32;
    const short8 kf =
        *(const short8*)(k_t + ((size_t)b * kN + kb + col) * 16 + h * 8);
    f32x16 c = {};
    c = __builtin_amdgcn_mfma_f32_32x32x16_bf16(kf, qf, c, 0, 0, 0);

    const f32x4 bv0 = *(const f32x4*)(bs + kb + 4 * h);
    const f32x4 bv1 = *(const f32x4*)(bs + kb + 8 + 4 * h);
    const f32x4 bv2 = *(const f32x4*)(bs + kb + 16 + 4 * h);
    const f32x4 bv3 = *(const f32x4*)(bs + kb + 24 + 4 * h);

    float s[16];
#pragma unroll
    for (int r = 0; r < 4; ++r)  s[r]      = fmaf(c[r],      kC1, bv0[r]);
#pragma unroll
    for (int r = 0; r < 4; ++r)  s[4 + r]  = fmaf(c[4 + r],  kC1, bv1[r]);
#pragma unroll
    for (int r = 0; r < 4; ++r)  s[8 + r]  = fmaf(c[8 + r],  kC1, bv2[r]);
#pragma unroll
    for (int r = 0; r < 4; ++r)  s[12 + r] = fmaf(c[12 + r], kC1, bv3[r]);

    float tmax = s[0];
#pragma unroll
    for (int r = 1; r < 16; ++r) tmax = fmaxf(tmax, s[r]);
    tmax = fmaxf(tmax, __shfl_xor(tmax, 32));

    const bool upd = tmax > m + 8.0f;   // defer-max (log2 domain)
    if (__any(upd)) {
      const float alpha = upd ? exp2f(m - tmax) : 1.0f;
      m = upd ? tmax : m;
      l *= alpha;
#pragma unroll
      for (int r = 0; r < 16; ++r) { o0[r] *= alpha; o1[r] *= alpha; }
    }

    short8 p0, p1;
    float lsum = 0.f;
#pragma unroll
    for (int e = 0; e < 8; ++e) {
      const float pe = exp2f(s[e] - m);
      lsum += pe;
      p0[e] = (short)f2bf(pe);
    }
#pragma unroll
    for (int e = 0; e < 8; ++e) {
      const float pe = exp2f(s[8 + e] - m);
      lsum += pe;
      p1[e] = (short)f2bf(pe);
    }
    l += lsum;

    const short8 vf00 = *(const short8*)(vb0 + kb + h * 8);
    const short8 vf01 = *(const short8*)(vb0 + kb + 16 + h * 8);
    const short8 vf10 = *(const short8*)(vb1 + kb + h * 8);
    const short8 vf11 = *(const short8*)(vb1 + kb + 16 + h * 8);
    o0 = __builtin_amdgcn_mfma_f32_32x32x16_bf16(vf00, p0, o0, 0, 0, 0);
    o0 = __builtin_amdgcn_mfma_f32_32x32x16_bf16(vf01, p1, o0, 0, 0, 0);
    o1 = __builtin_amdgcn_mfma_f32_32x32x16_bf16(vf10, p0, o1, 0, 0, 0);
    o1 = __builtin_amdgcn_mfma_f32_32x32x16_bf16(vf11, p1, o1, 0, 0, 0);
  }

  l += __shfl_xor(l, 32);  // both halves now hold the query's full l

  float* op = o_part + (size_t)w * 2048 + lane * 32;
#pragma unroll
  for (int r = 0; r < 16; ++r) {
    op[r] = o0[r];
    op[16 + r] = o1[r];
  }
  ml_part[(size_t)w * 128 + lane * 2]     = m;
  ml_part[(size_t)w * 128 + lane * 2 + 1] = l;
}

// ---------------------------------------------------------------------------
// Kernel 3b: combine split-K partials + epilogue. One wave per (b, qt).
// Writes bf16 o_bf (proj input) and, for heads 0-2, adds the head output
// into the NEXT head's cbn slice (fused cascade add).
// ---------------------------------------------------------------------------
__global__ __launch_bounds__(256) void attn_combine_kernel(
    const float* __restrict__ o_part, const float* __restrict__ ml_part,
    float* __restrict__ cbn_next, unsigned short* __restrict__ o_bf,
    int head, int do_cascade) {
  const int lane = threadIdx.x & 63;
  const int wid = threadIdx.x >> 6;
  const int w = blockIdx.x * 4 + wid;   // b*50 + qt
  if (w >= kB * kQT) return;
  const int b = w / kQT;
  const int qt = w - b * kQT;
  const int col = lane & 31;
  const int h = lane >> 5;
  const int nq = qt * 32 + col;

  const size_t base = (size_t)w * kNC;
  float mc[kNC], lc[kNC];
  float M = -3.0e38f;
#pragma unroll
  for (int c = 0; c < kNC; ++c) {
    mc[c] = ml_part[(base + c) * 128 + lane * 2];
    lc[c] = ml_part[(base + c) * 128 + lane * 2 + 1];
    M = fmaxf(M, mc[c]);
  }
  float o[32] = {};
  float l_tot = 0.f;
#pragma unroll
  for (int c = 0; c < kNC; ++c) {
    const float sc = exp2f(mc[c] - M);
    l_tot = fmaf(lc[c], sc, l_tot);
    const float* op = o_part + (base + c) * 2048 + lane * 32;
#pragma unroll
    for (int r = 0; r < 32; ++r) o[r] = fmaf(op[r], sc, o[r]);
  }
  const float inv = 1.0f / l_tot;

  float* cb = cbn_next + (size_t)b * kHD * kN + nq;
  unsigned short* obf = o_bf + ((size_t)b * kN + nq) * kDIM + head * kD;
#pragma unroll
  for (int r = 0; r < 16; ++r) {
    const int dim = (r & 3) + 8 * (r >> 2) + 4 * h;
    const float v0 = o[r] * inv;
    const float v1 = o[16 + r] * inv;
    if (do_cascade) {
      cb[(size_t)dim * kN] += v0;
      cb[(size_t)(32 + dim) * kN] += v1;
    }
    obf[dim] = f2bf(v0);
    obf[dim + 32] = f2bf(v1);
  }
}

// ---------------------------------------------------------------------------
// Kernel 4: projection GEMM via MFMA. C[o, (b,n)] = W[o,c] * o_bf[(b,n), c].
// ---------------------------------------------------------------------------
__global__ __launch_bounds__(256) void proj_mfma_kernel(
    const unsigned short* __restrict__ o_bf,   // (B, N, 256) bf16
    const unsigned short* __restrict__ w_bf,   // (256, 256) bf16
    const float* __restrict__ psc, const float* __restrict__ psh,
    float* __restrict__ out) {
  const int lane = threadIdx.x & 63;
  const int wid = threadIdx.x >> 6;
  const int t = blockIdx.x * 4 + wid;          // [0, 6400)
  const int b = t / 400;
  const int rem = t - b * 400;
  const int ot = rem / 50;
  const int nt = rem - ot * 50;
  const int col = lane & 31;
  const int h = lane >> 5;

  const unsigned short* arow = w_bf + ((size_t)(ot * 32 + col)) * kDIM + h * 8;
  const unsigned short* brow =
      o_bf + ((size_t)(b * kN + nt * 32 + col)) * kDIM + h * 8;

  f32x16 acc = {};
#pragma unroll
  for (int k = 0; k < 16; ++k) {
    const short8 af = *(const short8*)(arow + k * 16);
    const short8 bfr = *(const short8*)(brow + k * 16);
    acc = __builtin_amdgcn_mfma_f32_32x32x16_bf16(af, bfr, acc, 0, 0, 0);
  }

  float* ob = out + (size_t)b * kDIM * kN + nt * 32 + col;
#pragma unroll
  for (int r = 0; r < 16; ++r) {
    const int o = ot * 32 + (r & 3) + 8 * (r >> 2) + 4 * h;
    const float v = acc[r] * psc[o] + psh[o];
    ob[(size_t)o * kN] = fmaxf(v, 0.f);
  }
}

// ---------------------------------------------------------------------------
extern "C" void kernel_launch(void* const* d_in, const int* in_sizes, int n_in,
                              void* d_out, int out_size, void* d_ws,
                              size_t ws_size, hipStream_t stream) {
  const float* x      = (const float*)d_in[0];
  const float* dw_w   = (const float*)d_in[1];
  const float* dw_g   = (const float*)d_in[2];
  const float* dw_b   = (const float*)d_in[3];
  const float* dw_m   = (const float*)d_in[4];
  const float* dw_v   = (const float*)d_in[5];
  const float* q_w    = (const float*)d_in[6];
  const float* q_g    = (const float*)d_in[7];
  const float* q_b    = (const float*)d_in[8];
  const float* q_m    = (const float*)d_in[9];
  const float* q_v    = (const float*)d_in[10];
  const float* k_w    = (const float*)d_in[11];
  const float* k_g    = (const float*)d_in[12];
  const float* k_b    = (const float*)d_in[13];
  const float* k_m    = (const float*)d_in[14];
  const float* k_v    = (const float*)d_in[15];
  const float* v_w    = (const float*)d_in[16];
  const float* v_g    = (const float*)d_in[17];
  const float* v_b    = (const float*)d_in[18];
  const float* v_m    = (const float*)d_in[19];
  const float* v_v    = (const float*)d_in[20];
  const float* proj_w = (const float*)d_in[21];
  const float* proj_g = (const float*)d_in[22];
  const float* proj_b = (const float*)d_in[23];
  const float* proj_m = (const float*)d_in[24];
  const float* proj_v = (const float*)d_in[25];
  const float* attn_bias = (const float*)d_in[26];

  // Workspace layout:
  float* ws = (float*)d_ws;
  float* cbn   = ws;                                     // 4*B*64*N f32
  float* bias2 = cbn + (size_t)kNH * kB * kHD * kN;      // 4*N f32
  float* psc   = bias2 + kNH * kN;                       // 256 f32
  float* psh   = psc + kDIM;                             // 256 f32
  unsigned short* q_t = (unsigned short*)(psh + kDIM);   // B*N*16 bf16
  unsigned short* k_t = q_t + (size_t)kB * kN * kKD;     // B*N*16 bf16
  unsigned short* v_p = k_t + (size_t)kB * kN * kKD;     // B*64*N bf16
  unsigned short* o_bf = v_p + (size_t)kB * kD * kN;     // B*N*256 bf16
  unsigned short* w_bf = o_bf + (size_t)kB * kN * kDIM;  // 256*256 bf16
  float* o_part = (float*)(w_bf + (size_t)kDIM * kDIM);  // B*50*5*2048 f32
  float* ml_part = o_part + (size_t)kB * kQT * kNC * 2048;  // B*50*5*128 f32

  prep_kernel<<<(kDIM * kDIM + 255) / 256, 256, 0, stream>>>(
      attn_bias, proj_w, proj_g, proj_b, proj_m, proj_v, bias2, w_bf, psc,
      psh);

  conv_all_kernel<<<kB * kDIM, 256, 0, stream>>>(x, dw_w, dw_g, dw_b, dw_m,
                                                 dw_v, cbn);

  const size_t slice = (size_t)kB * kHD * kN;
  const int split_waves = kB * kQT * kNC;      // 4000
  const int comb_waves = kB * kQT;             // 800

  for (int head = 0; head < kNH; ++head) {
    const float* xi = cbn + (size_t)head * slice;

    qk_t_kernel<<<(kB * kN) / 256, 256, 0, stream>>>(
        xi, q_w, q_g, q_b, q_m, q_v, k_w, k_g, k_b, k_m, k_v, q_t, k_t,
        head);

    v_perm_kernel<<<(kB * kD * kN) / 256, 256, 0, stream>>>(
        xi, v_w, v_g, v_b, v_m, v_v, v_p, head);

    attn_split_kernel<<<split_waves / 4, 256, 0, stream>>>(
        q_t, k_t, v_p, bias2, o_part, ml_part, head);

    float* cbn_next = cbn + (size_t)(head + 1) * slice;  // unused for head 3
    attn_combine_kernel<<<comb_waves / 4, 256, 0, stream>>>(
        o_part, ml_part, head < 3 ? cbn_next : cbn, o_bf, head,
        head < 3 ? 1 : 0);
  }

  proj_mfma_kernel<<<1600, 256, 0, stream>>>(o_bf, w_bf, psc, psh,
                                             (float*)d_out);
}

// Round 7
// 402.269 us; speedup vs baseline: 1.8062x; 1.4713x over previous
//
#include <hip/hip_runtime.h>
#include <cstddef>

namespace {
constexpr int kNH  = 4;
constexpr int kKD  = 16;
constexpr int kHD  = 64;
constexpr int kD   = 64;
constexpr int kRES = 40;
constexpr int kN   = 1600;   // 40*40
constexpr int kB   = 16;
constexpr int kDIM = 256;
constexpr int kQT  = kN / 32;        // 50 query tiles
constexpr int kNC  = 5;              // key chunks (split-K)
constexpr int kTPC = kQT / kNC;      // 10 key tiles per chunk
constexpr float kEPS   = 1e-5f;
constexpr float kSCALE = 0.25f;          // KD^-0.5
constexpr float kLOG2E = 1.4426950408889634f;
constexpr float kC1    = kSCALE * kLOG2E;
}  // namespace

typedef __attribute__((ext_vector_type(8)))  short short8;
typedef __attribute__((ext_vector_type(4)))  short s16x4;
typedef __attribute__((ext_vector_type(4)))  float f32x4;
typedef __attribute__((ext_vector_type(16))) float f32x16;

// f32 -> bf16 bits, round-nearest-even (values here are finite).
static __device__ __forceinline__ unsigned short f2bf(float x) {
  unsigned u = __builtin_bit_cast(unsigned, x);
  u = (u + 0x7fffu + ((u >> 16) & 1u)) >> 16;
  return (unsigned short)u;
}

// ---------------------------------------------------------------------------
// Kernel 0: prep — bias2; proj_w->bf16 + BN fold; qkv weights->bf16 (MFMA
// layouts) + folded qkv BN scale/shift.
// ---------------------------------------------------------------------------
__global__ __launch_bounds__(256) void prep_kernel(
    const float* __restrict__ attn_bias, const float* __restrict__ proj_w,
    const float* __restrict__ pg, const float* __restrict__ pb,
    const float* __restrict__ pm, const float* __restrict__ pv,
    const float* __restrict__ q_w, const float* __restrict__ q_g,
    const float* __restrict__ q_b, const float* __restrict__ q_m,
    const float* __restrict__ q_v,
    const float* __restrict__ k_w, const float* __restrict__ k_g,
    const float* __restrict__ k_b, const float* __restrict__ k_m,
    const float* __restrict__ k_v,
    const float* __restrict__ v_w, const float* __restrict__ v_g,
    const float* __restrict__ v_b, const float* __restrict__ v_m,
    const float* __restrict__ v_v,
    float* __restrict__ bias2, unsigned short* __restrict__ w_bf,
    float* __restrict__ psc, float* __restrict__ psh,
    unsigned short* __restrict__ w_qk, unsigned short* __restrict__ w_vv,
    float* __restrict__ qkv_sc, float* __restrict__ qkv_sh) {
  const int i = blockIdx.x * 256 + threadIdx.x;
  if (i < kNH * kN) bias2[i] = attn_bias[i] * kLOG2E;
  if (i < kDIM * kDIM) w_bf[i] = f2bf(proj_w[i]);
  if (i < kDIM) {
    const float sc = pg[i] * rsqrtf(pv[i] + kEPS);
    psc[i] = sc;
    psh[i] = pb[i] - pm[i] * sc;
  }
  if (i < kNH * 32 * kHD) {  // (head, ch[0,32), c) ; ch<16 q, else k
    const int head = i >> 11;
    const int ch = (i >> 6) & 31;
    const int c = i & 63;
    const float wv = (ch < 16) ? q_w[head * 1024 + ch * 64 + c]
                               : k_w[head * 1024 + (ch - 16) * 64 + c];
    w_qk[i] = f2bf(wv);
  }
  if (i < kNH * kD * kHD) w_vv[i] = f2bf(v_w[i]);  // same flat layout
  if (i < kNH * 96) {
    const int head = i / 96;
    const int ch = i - head * 96;
    float g, bb, mm, vv;
    if (ch < 16) {
      const int r = head * 16 + ch;
      g = q_g[r]; bb = q_b[r]; mm = q_m[r]; vv = q_v[r];
    } else if (ch < 32) {
      const int r = head * 16 + (ch - 16);
      g = k_g[r]; bb = k_b[r]; mm = k_m[r]; vv = k_v[r];
    } else {
      const int r = head * 64 + (ch - 32);
      g = v_g[r]; bb = v_b[r]; mm = v_m[r]; vv = v_v[r];
    }
    const float sc = g * rsqrtf(vv + kEPS);
    qkv_sc[i] = sc;
    qkv_sh[i] = bb - mm * sc;
  }
}

// ---------------------------------------------------------------------------
// Kernel 1: depthwise 5x5 conv (SAME) + BN for ALL 4 heads. Writes f32 cbn
// (cascade source for heads 1-3) and, for head 0, the bf16 x_t (b,n,c)
// MFMA-ready transposed layout.
// ---------------------------------------------------------------------------
__global__ __launch_bounds__(256) void conv_all_kernel(
    const float* __restrict__ x,
    const float* __restrict__ dw_w, const float* __restrict__ dw_g,
    const float* __restrict__ dw_b, const float* __restrict__ dw_m,
    const float* __restrict__ dw_v,
    float* __restrict__ cbn, unsigned short* __restrict__ x_t) {
  __shared__ float P[44 * 44];
  const int blk = blockIdx.x;          // b*256 + gc
  const int b = blk >> 8;
  const int gc = blk & 255;
  const int head = gc >> 6;
  const int c = gc & 63;
  const int tid = threadIdx.x;

  for (int i = tid; i < 44 * 44; i += 256) P[i] = 0.f;
  __syncthreads();

  const float* xin = x + ((size_t)b * kDIM + gc) * kN;
  for (int i = tid; i < kN; i += 256) {
    const int r = i / kRES;
    const int col = i - r * kRES;
    P[(r + 2) * 44 + col + 2] = xin[i];
  }

  float wreg[25];
  const float* wc = dw_w + (size_t)gc * 25;
#pragma unroll
  for (int t = 0; t < 25; ++t) wreg[t] = wc[t];
  const float sc = dw_g[gc] * rsqrtf(dw_v[gc] + kEPS);
  const float sh = dw_b[gc] - dw_m[gc] * sc;

  __syncthreads();

  if (tid < 200) {
    const int h = tid / 5;             // row
    const int w0 = (tid - h * 5) * 8;  // segment start col
    float acc[8] = {};
#pragma unroll
    for (int dh = 0; dh < 5; ++dh) {
      float t[12];
      const float* row = P + (h + dh) * 44 + w0;
#pragma unroll
      for (int i = 0; i < 12; ++i) t[i] = row[i];
#pragma unroll
      for (int j = 0; j < 8; ++j)
#pragma unroll
        for (int i = 0; i < 5; ++i)
          acc[j] = fmaf(t[j + i], wreg[dh * 5 + i], acc[j]);
    }
    float* xo = cbn + ((size_t)head * kB * kHD + (size_t)b * kHD + c) * kN +
                h * kRES + w0;
    f32x4 o0, o1;
#pragma unroll
    for (int j = 0; j < 4; ++j) {
      o0[j] = acc[j] * sc + sh;
      o1[j] = acc[4 + j] * sc + sh;
    }
    *(f32x4*)xo = o0;
    *(f32x4*)(xo + 4) = o1;
    if (head == 0) {
      unsigned short* xr =
          x_t + (((size_t)b * kN) + h * kRES + w0) * 64 + c;
#pragma unroll
      for (int j = 0; j < 4; ++j) {
        xr[(size_t)j * 64] = f2bf(o0[j]);
        xr[(size_t)(4 + j) * 64] = f2bf(o1[j]);
      }
    }
  }
}

// ---------------------------------------------------------------------------
// Kernel 2: fused QKV via MFMA. Per b: 50 QK waves + 100 V waves.
// QK: C = mfma(A=W_qk(32ch x 64), B=X(32n x 64)) -> col=n, row=ch; writes
//     q_t/k_t (b,n,16) rows in 8B chunks.
// V:  C = mfma(A=X(32n x 64), B=W_v(32d x 64)) -> col=d, row=n; 4-chunks of
//     n align with sigma-chunks; writes v_p (b,d,sigma(n)) in 8B chunks.
// ---------------------------------------------------------------------------
__global__ __launch_bounds__(256) void qkv_mfma_kernel(
    const unsigned short* __restrict__ x_t,   // (B,N,64) this head
    const unsigned short* __restrict__ w_qk,  // (32,64) this head
    const unsigned short* __restrict__ w_v,   // (64,64) this head
    const float* __restrict__ qsc,            // (96) folded, this head
    const float* __restrict__ qsh,
    unsigned short* __restrict__ q_t, unsigned short* __restrict__ k_t,
    unsigned short* __restrict__ v_p) {
  const int lane = threadIdx.x & 63;
  const int wid = threadIdx.x >> 6;
  const int w = blockIdx.x * 4 + wid;   // [0, 2400)
  const int b = w / 150;
  const int r = w - b * 150;
  const int col = lane & 31;
  const int h = lane >> 5;

  if (r < kQT) {  // ---- QK wave ----
    const int n0 = r * 32;
    const unsigned short* ax = w_qk + (size_t)col * 64 + h * 8;
    const unsigned short* bx = x_t + ((size_t)b * kN + n0 + col) * 64 + h * 8;
    f32x16 acc = {};
#pragma unroll
    for (int kk = 0; kk < 4; ++kk) {
      const short8 af = *(const short8*)(ax + kk * 16);
      const short8 bf = *(const short8*)(bx + kk * 16);
      acc = __builtin_amdgcn_mfma_f32_32x32x16_bf16(af, bf, acc, 0, 0, 0);
    }
    const int n = n0 + col;
    unsigned short* qrow = q_t + ((size_t)b * kN + n) * 16;
    unsigned short* krow = k_t + ((size_t)b * kN + n) * 16;
#pragma unroll
    for (int g = 0; g < 4; ++g) {
      const int ch0 = g * 8 + 4 * h;   // {0,8,16,24}+4h
      const f32x4 s4 = *(const f32x4*)(qsc + ch0);
      const f32x4 h4 = *(const f32x4*)(qsh + ch0);
      s16x4 pk;
#pragma unroll
      for (int j = 0; j < 4; ++j)
        pk[j] = (short)f2bf(acc[g * 4 + j] * s4[j] + h4[j]);
      if (ch0 < 16) *(s16x4*)(qrow + ch0) = pk;
      else          *(s16x4*)(krow + ch0 - 16) = pk;
    }
  } else {  // ---- V wave ----
    const int idx = r - kQT;           // [0,100)
    const int dt = idx / kQT;          // 0..1
    const int nt = idx - dt * kQT;
    const int n0 = nt * 32;
    const int d = dt * 32 + col;
    const unsigned short* ax = x_t + ((size_t)b * kN + n0 + col) * 64 + h * 8;
    const unsigned short* bx = w_v + (size_t)d * 64 + h * 8;
    f32x16 acc = {};
#pragma unroll
    for (int kk = 0; kk < 4; ++kk) {
      const short8 af = *(const short8*)(ax + kk * 16);
      const short8 bf = *(const short8*)(bx + kk * 16);
      acc = __builtin_amdgcn_mfma_f32_32x32x16_bf16(af, bf, acc, 0, 0, 0);
    }
    const float sc = qsc[32 + d];
    const float sh = qsh[32 + d];
    unsigned short* vrow = v_p + ((size_t)(b * kD) + d) * kN + n0;
#pragma unroll
    for (int g = 0; g < 4; ++g) {
      const int rr0 = g * 8 + 4 * h;   // n-chunk start within 32
      const int low = rr0 & 15;
      const int pos = (rr0 & 16) | (low & 3) | ((low & 4) << 1) |
                      ((low & 8) >> 1);  // sigma(chunk start)
      s16x4 pk;
#pragma unroll
      for (int j = 0; j < 4; ++j)
        pk[j] = (short)f2bf(acc[g * 4 + j] * sc + sh);
      *(s16x4*)(vrow + pos) = pk;
    }
  }
}

// ---------------------------------------------------------------------------
// Kernel 3a: split-K MFMA flash attention (unchanged, HW-verified).
// ---------------------------------------------------------------------------
__global__ __launch_bounds__(256) void attn_split_kernel(
    const unsigned short* __restrict__ q_t,
    const unsigned short* __restrict__ k_t,
    const unsigned short* __restrict__ v_p,
    const float* __restrict__ bias2,
    float* __restrict__ o_part,    // [B*QT*NC][64 lanes][32] f32
    float* __restrict__ ml_part,   // [B*QT*NC][64 lanes][2] f32
    int head) {
  const int lane = threadIdx.x & 63;
  const int wid = threadIdx.x >> 6;
  const int w = blockIdx.x * 4 + wid;
  if (w >= kB * kQT * kNC) return;
  const int b = w / (kQT * kNC);
  const int rem = w - b * (kQT * kNC);
  const int qt = rem / kNC;
  const int chunk = rem - qt * kNC;
  const int col = lane & 31;
  const int h = lane >> 5;
  const int nq = qt * 32 + col;

  const short8 qf =
      *(const short8*)(q_t + ((size_t)b * kN + nq) * 16 + h * 8);
  const float* bs = bias2 + (size_t)head * kN;
  const unsigned short* vb0 = v_p + ((size_t)(b * kD) + col) * kN;
  const unsigned short* vb1 = v_p + ((size_t)(b * kD) + 32 + col) * kN;

  f32x16 o0 = {}, o1 = {};
  float m = -3.0e38f, l = 0.f;

  for (int kt = chunk * kTPC; kt < (chunk + 1) * kTPC; ++kt) {
    const int kb = kt * 32;
    const short8 kf =
        *(const short8*)(k_t + ((size_t)b * kN + kb + col) * 16 + h * 8);
    f32x16 c = {};
    c = __builtin_amdgcn_mfma_f32_32x32x16_bf16(kf, qf, c, 0, 0, 0);

    const f32x4 bv0 = *(const f32x4*)(bs + kb + 4 * h);
    const f32x4 bv1 = *(const f32x4*)(bs + kb + 8 + 4 * h);
    const f32x4 bv2 = *(const f32x4*)(bs + kb + 16 + 4 * h);
    const f32x4 bv3 = *(const f32x4*)(bs + kb + 24 + 4 * h);

    float s[16];
#pragma unroll
    for (int r = 0; r < 4; ++r)  s[r]      = fmaf(c[r],      kC1, bv0[r]);
#pragma unroll
    for (int r = 0; r < 4; ++r)  s[4 + r]  = fmaf(c[4 + r],  kC1, bv1[r]);
#pragma unroll
    for (int r = 0; r < 4; ++r)  s[8 + r]  = fmaf(c[8 + r],  kC1, bv2[r]);
#pragma unroll
    for (int r = 0; r < 4; ++r)  s[12 + r] = fmaf(c[12 + r], kC1, bv3[r]);

    float tmax = s[0];
#pragma unroll
    for (int r = 1; r < 16; ++r) tmax = fmaxf(tmax, s[r]);
    tmax = fmaxf(tmax, __shfl_xor(tmax, 32));

    const bool upd = tmax > m + 8.0f;   // defer-max (log2 domain)
    if (__any(upd)) {
      const float alpha = upd ? exp2f(m - tmax) : 1.0f;
      m = upd ? tmax : m;
      l *= alpha;
#pragma unroll
      for (int r = 0; r < 16; ++r) { o0[r] *= alpha; o1[r] *= alpha; }
    }

    short8 p0, p1;
    float lsum = 0.f;
#pragma unroll
    for (int e = 0; e < 8; ++e) {
      const float pe = exp2f(s[e] - m);
      lsum += pe;
      p0[e] = (short)f2bf(pe);
    }
#pragma unroll
    for (int e = 0; e < 8; ++e) {
      const float pe = exp2f(s[8 + e] - m);
      lsum += pe;
      p1[e] = (short)f2bf(pe);
    }
    l += lsum;

    const short8 vf00 = *(const short8*)(vb0 + kb + h * 8);
    const short8 vf01 = *(const short8*)(vb0 + kb + 16 + h * 8);
    const short8 vf10 = *(const short8*)(vb1 + kb + h * 8);
    const short8 vf11 = *(const short8*)(vb1 + kb + 16 + h * 8);
    o0 = __builtin_amdgcn_mfma_f32_32x32x16_bf16(vf00, p0, o0, 0, 0, 0);
    o0 = __builtin_amdgcn_mfma_f32_32x32x16_bf16(vf01, p1, o0, 0, 0, 0);
    o1 = __builtin_amdgcn_mfma_f32_32x32x16_bf16(vf10, p0, o1, 0, 0, 0);
    o1 = __builtin_amdgcn_mfma_f32_32x32x16_bf16(vf11, p1, o1, 0, 0, 0);
  }

  l += __shfl_xor(l, 32);

  float* op = o_part + (size_t)w * 2048 + lane * 32;
#pragma unroll
  for (int r = 0; r < 16; ++r) {
    op[r] = o0[r];
    op[16 + r] = o1[r];
  }
  ml_part[(size_t)w * 128 + lane * 2]     = m;
  ml_part[(size_t)w * 128 + lane * 2 + 1] = l;
}

// ---------------------------------------------------------------------------
// Kernel 3b: combine split-K partials + epilogue. Writes bf16 o_bf (proj
// input, 8B chunks) and, for heads 0-2, x_t_next = bf16(conv_next + o)
// (fused cascade add in f32).
// ---------------------------------------------------------------------------
__global__ __launch_bounds__(256) void attn_combine_kernel(
    const float* __restrict__ o_part, const float* __restrict__ ml_part,
    const float* __restrict__ cbn_next, unsigned short* __restrict__ x_t_next,
    unsigned short* __restrict__ o_bf, int head, int do_cascade) {
  const int lane = threadIdx.x & 63;
  const int wid = threadIdx.x >> 6;
  const int w = blockIdx.x * 4 + wid;   // b*50 + qt
  if (w >= kB * kQT) return;
  const int b = w / kQT;
  const int qt = w - b * kQT;
  const int col = lane & 31;
  const int h = lane >> 5;
  const int nq = qt * 32 + col;

  const size_t base = (size_t)w * kNC;
  float mc[kNC], lc[kNC];
  float M = -3.0e38f;
#pragma unroll
  for (int c = 0; c < kNC; ++c) {
    mc[c] = ml_part[(base + c) * 128 + lane * 2];
    lc[c] = ml_part[(base + c) * 128 + lane * 2 + 1];
    M = fmaxf(M, mc[c]);
  }
  float o[32] = {};
  float l_tot = 0.f;
#pragma unroll
  for (int c = 0; c < kNC; ++c) {
    const float sc = exp2f(mc[c] - M);
    l_tot = fmaf(lc[c], sc, l_tot);
    const float* op = o_part + (base + c) * 2048 + lane * 32;
#pragma unroll
    for (int r = 0; r < 32; ++r) o[r] = fmaf(op[r], sc, o[r]);
  }
  const float inv = 1.0f / l_tot;

  unsigned short* obf = o_bf + ((size_t)b * kN + nq) * kDIM + head * kD;
  if (do_cascade) {
    const float* cb = cbn_next + (size_t)b * kHD * kN + nq;
    unsigned short* xrow = x_t_next + ((size_t)b * kN + nq) * 64;
#pragma unroll
    for (int g = 0; g < 4; ++g) {
      const int d0 = g * 8 + 4 * h;
      s16x4 po0, po1, px0, px1;
#pragma unroll
      for (int j = 0; j < 4; ++j) {
        const int dim = d0 + j;
        const float v0 = o[g * 4 + j] * inv;
        const float v1 = o[16 + g * 4 + j] * inv;
        po0[j] = (short)f2bf(v0);
        po1[j] = (short)f2bf(v1);
        px0[j] = (short)f2bf(cb[(size_t)dim * kN] + v0);
        px1[j] = (short)f2bf(cb[(size_t)(dim + 32) * kN] + v1);
      }
      *(s16x4*)(obf + d0) = po0;
      *(s16x4*)(obf + d0 + 32) = po1;
      *(s16x4*)(xrow + d0) = px0;
      *(s16x4*)(xrow + d0 + 32) = px1;
    }
  } else {
#pragma unroll
    for (int g = 0; g < 4; ++g) {
      const int d0 = g * 8 + 4 * h;
      s16x4 po0, po1;
#pragma unroll
      for (int j = 0; j < 4; ++j) {
        po0[j] = (short)f2bf(o[g * 4 + j] * inv);
        po1[j] = (short)f2bf(o[16 + g * 4 + j] * inv);
      }
      *(s16x4*)(obf + d0) = po0;
      *(s16x4*)(obf + d0 + 32) = po1;
    }
  }
}

// ---------------------------------------------------------------------------
// Kernel 4: projection GEMM via MFMA (unchanged, HW-verified).
// ---------------------------------------------------------------------------
__global__ __launch_bounds__(256) void proj_mfma_kernel(
    const unsigned short* __restrict__ o_bf,   // (B, N, 256) bf16
    const unsigned short* __restrict__ w_bf,   // (256, 256) bf16
    const float* __restrict__ psc, const float* __restrict__ psh,
    float* __restrict__ out) {
  const int lane = threadIdx.x & 63;
  const int wid = threadIdx.x >> 6;
  const int t = blockIdx.x * 4 + wid;          // [0, 6400)
  const int b = t / 400;
  const int rem = t - b * 400;
  const int ot = rem / 50;
  const int nt = rem - ot * 50;
  const int col = lane & 31;
  const int h = lane >> 5;

  const unsigned short* arow = w_bf + ((size_t)(ot * 32 + col)) * kDIM + h * 8;
  const unsigned short* brow =
      o_bf + ((size_t)(b * kN + nt * 32 + col)) * kDIM + h * 8;

  f32x16 acc = {};
#pragma unroll
  for (int k = 0; k < 16; ++k) {
    const short8 af = *(const short8*)(arow + k * 16);
    const short8 bfr = *(const short8*)(brow + k * 16);
    acc = __builtin_amdgcn_mfma_f32_32x32x16_bf16(af, bfr, acc, 0, 0, 0);
  }

  float* ob = out + (size_t)b * kDIM * kN + nt * 32 + col;
#pragma unroll
  for (int r = 0; r < 16; ++r) {
    const int o = ot * 32 + (r & 3) + 8 * (r >> 2) + 4 * h;
    const float v = acc[r] * psc[o] + psh[o];
    ob[(size_t)o * kN] = fmaxf(v, 0.f);
  }
}

// ---------------------------------------------------------------------------
extern "C" void kernel_launch(void* const* d_in, const int* in_sizes, int n_in,
                              void* d_out, int out_size, void* d_ws,
                              size_t ws_size, hipStream_t stream) {
  const float* x      = (const float*)d_in[0];
  const float* dw_w   = (const float*)d_in[1];
  const float* dw_g   = (const float*)d_in[2];
  const float* dw_b   = (const float*)d_in[3];
  const float* dw_m   = (const float*)d_in[4];
  const float* dw_v   = (const float*)d_in[5];
  const float* q_w    = (const float*)d_in[6];
  const float* q_g    = (const float*)d_in[7];
  const float* q_b    = (const float*)d_in[8];
  const float* q_m    = (const float*)d_in[9];
  const float* q_v    = (const float*)d_in[10];
  const float* k_w    = (const float*)d_in[11];
  const float* k_g    = (const float*)d_in[12];
  const float* k_b    = (const float*)d_in[13];
  const float* k_m    = (const float*)d_in[14];
  const float* k_v    = (const float*)d_in[15];
  const float* v_w    = (const float*)d_in[16];
  const float* v_g    = (const float*)d_in[17];
  const float* v_b    = (const float*)d_in[18];
  const float* v_m    = (const float*)d_in[19];
  const float* v_v    = (const float*)d_in[20];
  const float* proj_w = (const float*)d_in[21];
  const float* proj_g = (const float*)d_in[22];
  const float* proj_b = (const float*)d_in[23];
  const float* proj_m = (const float*)d_in[24];
  const float* proj_v = (const float*)d_in[25];
  const float* attn_bias = (const float*)d_in[26];

  // Workspace layout:
  float* ws = (float*)d_ws;
  float* cbn    = ws;                                    // 4*B*64*N f32
  float* bias2  = cbn + (size_t)kNH * kB * kHD * kN;     // 4*N f32
  float* psc    = bias2 + kNH * kN;                      // 256 f32
  float* psh    = psc + kDIM;                            // 256 f32
  float* qkv_sc = psh + kDIM;                            // 4*96 f32
  float* qkv_sh = qkv_sc + kNH * 96;                     // 4*96 f32
  unsigned short* q_t  = (unsigned short*)(qkv_sh + kNH * 96);  // B*N*16
  unsigned short* k_t  = q_t + (size_t)kB * kN * kKD;           // B*N*16
  unsigned short* v_p  = k_t + (size_t)kB * kN * kKD;           // B*64*N
  unsigned short* o_bf = v_p + (size_t)kB * kD * kN;            // B*N*256
  unsigned short* w_bf = o_bf + (size_t)kB * kN * kDIM;         // 256*256
  unsigned short* x_t  = w_bf + (size_t)kDIM * kDIM;            // 4*B*N*64
  unsigned short* w_qk = x_t + (size_t)kNH * kB * kN * 64;      // 4*32*64
  unsigned short* w_vv = w_qk + (size_t)kNH * 32 * kHD;         // 4*64*64
  float* o_part = (float*)(w_vv + (size_t)kNH * kD * kHD);      // B*250*2048
  float* ml_part = o_part + (size_t)kB * kQT * kNC * 2048;      // B*250*128

  prep_kernel<<<(kDIM * kDIM + 255) / 256, 256, 0, stream>>>(
      attn_bias, proj_w, proj_g, proj_b, proj_m, proj_v,
      q_w, q_g, q_b, q_m, q_v, k_w, k_g, k_b, k_m, k_v,
      v_w, v_g, v_b, v_m, v_v,
      bias2, w_bf, psc, psh, w_qk, w_vv, qkv_sc, qkv_sh);

  conv_all_kernel<<<kB * kDIM, 256, 0, stream>>>(x, dw_w, dw_g, dw_b, dw_m,
                                                 dw_v, cbn, x_t);

  const size_t cslice = (size_t)kB * kHD * kN;   // f32 conv slice
  const size_t xslice = (size_t)kB * kN * 64;    // bf16 x_t slice
  const int split_waves = kB * kQT * kNC;        // 4000
  const int comb_waves = kB * kQT;               // 800

  for (int head = 0; head < kNH; ++head) {
    qkv_mfma_kernel<<<600, 256, 0, stream>>>(
        x_t + (size_t)head * xslice, w_qk + (size_t)head * 32 * kHD,
        w_vv + (size_t)head * kD * kHD, qkv_sc + head * 96,
        qkv_sh + head * 96, q_t, k_t, v_p);

    attn_split_kernel<<<split_waves / 4, 256, 0, stream>>>(
        q_t, k_t, v_p, bias2, o_part, ml_part, head);

    attn_combine_kernel<<<comb_waves / 4, 256, 0, stream>>>(
        o_part, ml_part, cbn + (size_t)(head + 1) * cslice,
        x_t + (size_t)(head + 1) * xslice, o_bf, head, head < 3 ? 1 : 0);
  }

  proj_mfma_kernel<<<1600, 256, 0, stream>>>(o_bf, w_bf, psc, psh,
                                             (float*)d_out);
}